// Round 1
// baseline (771.311 us; speedup 1.0000x reference)
//
#include <hip/hip_runtime.h>

#define TT 512
#define HH 64
#define BPB 4      // batches per block -> 512 blocks
#define NTH 256

__device__ __forceinline__ float sigm(float x) {
    // 1/(1+e^-x); exp2(-inf)->0 => 1, exp2(+inf)->inf => rcp->0. Safe.
    return __builtin_amdgcn_rcpf(1.f + __builtin_amdgcn_exp2f(-1.4426950408889634f * x));
}
__device__ __forceinline__ float tanh_f(float x) {
    // 1 - 2/(e^{2x}+1); saturates correctly at +-1
    return 1.f - 2.f * __builtin_amdgcn_rcpf(1.f + __builtin_amdgcn_exp2f(2.8853900817779268f * x));
}

__global__ __launch_bounds__(NTH, 2)
void lstm_fused(const float* __restrict__ x,
                const float* __restrict__ W_ih,
                const float* __restrict__ W_hh,
                const float* __restrict__ b_ih,
                const float* __restrict__ b_hh,
                const float* __restrict__ W_fc,
                const float* __restrict__ b_fc,
                float* __restrict__ out)
{
    __shared__ float x_sh[BPB * TT * 4];       // 32 KB: x for this block's 4 batches
    __shared__ float h_sh[BPB * HH];           // 1 KB
    __shared__ float gate_sh[BPB * 4 * HH];    // 4 KB raw gates

    const int tid = threadIdx.x;
    const int b0 = blockIdx.x * BPB;

    // Stage x: the 4 batches are contiguous in global (b-major), 32 KB flat copy
    {
        const float4* src = (const float4*)(x + (size_t)b0 * TT * 4);
        float4* dst = (float4*)x_sh;
        #pragma unroll
        for (int i = 0; i < (BPB * TT) / NTH; ++i)   // 2048 float4 / 256 thr = 8
            dst[tid + i * NTH] = src[tid + i * NTH];
    }

    // Persistent weights: thread tid owns gate-row tid of W_hh (64 fp32 in VGPRs)
    float4 w4[16];
    {
        const float4* wr = (const float4*)(W_hh + tid * HH);
        #pragma unroll
        for (int i = 0; i < 16; ++i) w4[i] = wr[i];
    }
    const float4 xw = ((const float4*)W_ih)[tid];   // W_ih row tid (I=4)
    const float bias = b_ih[tid] + b_hh[tid];

    // Elementwise state: thread owns (b = tid>>6, u = tid&63)
    h_sh[tid] = 0.f;
    float c = 0.f;
    const int eb = tid >> 6, eu = tid & 63;

    __syncthreads();

    const float4* xs4 = (const float4*)x_sh;   // [BPB][TT] of float4
    const float4* h4  = (const float4*)h_sh;   // [BPB][16] of float4

    #pragma unroll 1
    for (int t = 0; t < TT; ++t) {
        // gate-row tid pre-activation for each of 4 batches
        float acc[BPB];
        #pragma unroll
        for (int b = 0; b < BPB; ++b) {
            float4 xv = xs4[b * TT + t];       // LDS broadcast
            acc[b] = fmaf(xw.x, xv.x, fmaf(xw.y, xv.y,
                     fmaf(xw.z, xv.z, fmaf(xw.w, xv.w, bias))));
        }
        #pragma unroll
        for (int kc = 0; kc < 16; ++kc) {
            const float4 w = w4[kc];
            #pragma unroll
            for (int b = 0; b < BPB; ++b) {
                float4 hv = h4[b * 16 + kc];   // LDS broadcast (all lanes same addr)
                acc[b] = fmaf(w.x, hv.x, acc[b]);
                acc[b] = fmaf(w.y, hv.y, acc[b]);
                acc[b] = fmaf(w.z, hv.z, acc[b]);
                acc[b] = fmaf(w.w, hv.w, acc[b]);
            }
        }
        #pragma unroll
        for (int b = 0; b < BPB; ++b)
            gate_sh[b * 256 + tid] = acc[b];   // stride-1 across lanes, no conflict
        __syncthreads();

        // LSTM cell update, one (b,u) per thread. Gate order i,f,g,o.
        {
            float gi = gate_sh[eb * 256 +       eu];
            float gf = gate_sh[eb * 256 +  64 + eu];
            float gg = gate_sh[eb * 256 + 128 + eu];
            float go = gate_sh[eb * 256 + 192 + eu];
            float tg = tanh_f(gg);
            c = sigm(gf) * c + sigm(gi) * tg;
            float hn = sigm(go) * tanh_f(c);
            h_sh[tid] = hn;                    // tid == eb*64+eu
        }
        __syncthreads();
    }

    // FC epilogue: out[1, B, 4]
    if (tid < BPB * 4) {
        const int b = tid >> 2, o = tid & 3;
        float s = b_fc[o];
        #pragma unroll
        for (int k = 0; k < HH; ++k)
            s = fmaf(h_sh[b * HH + k], W_fc[o * HH + k], s);
        out[(size_t)(b0 + b) * 4 + o] = s;
    }
}

extern "C" void kernel_launch(void* const* d_in, const int* in_sizes, int n_in,
                              void* d_out, int out_size, void* d_ws, size_t ws_size,
                              hipStream_t stream) {
    const float* x    = (const float*)d_in[0];
    const float* W_ih = (const float*)d_in[1];
    const float* W_hh = (const float*)d_in[2];
    const float* b_ih = (const float*)d_in[3];
    const float* b_hh = (const float*)d_in[4];
    const float* W_fc = (const float*)d_in[5];
    const float* b_fc = (const float*)d_in[6];
    float* out = (float*)d_out;
    lstm_fused<<<2048 / BPB, NTH, 0, stream>>>(x, W_ih, W_hh, b_ih, b_hh, W_fc, b_fc, out);
}

// Round 2
// 317.035 us; speedup vs baseline: 2.4329x; 2.4329x over previous
//
#include <hip/hip_runtime.h>

typedef _Float16 half8 __attribute__((ext_vector_type(8)));
typedef _Float16 half4 __attribute__((ext_vector_type(4)));
typedef float f32x4 __attribute__((ext_vector_type(4)));

#define TT   512
#define HH   64
#define MB   16     // batches per block -> 128 blocks
#define HSTR 72     // h_sh row stride (f16 units): 144B, conflict-optimal b128 reads
#define XSTR 260    // x_sh per-batch stride (f16 units): 520B, kills 128B aliasing

__device__ __forceinline__ float sigm(float x) {
    return __builtin_amdgcn_rcpf(1.f + __builtin_amdgcn_exp2f(-1.4426950408889634f * x));
}
__device__ __forceinline__ float tanh_f(float x) {
    return 1.f - 2.f * __builtin_amdgcn_rcpf(1.f + __builtin_amdgcn_exp2f(2.8853900817779268f * x));
}

__global__ __launch_bounds__(256, 1)
void lstm_mfma(const float* __restrict__ x,
               const float* __restrict__ W_ih,
               const float* __restrict__ W_hh,
               const float* __restrict__ b_ih,
               const float* __restrict__ b_hh,
               const float* __restrict__ W_fc,
               const float* __restrict__ b_fc,
               float* __restrict__ out)
{
    __shared__ _Float16 h_sh[2][MB * HSTR];   // double-buffered hidden state (f16)
    __shared__ _Float16 x_sh[MB * XSTR];      // 64-timestep x chunk (f16)

    const int tid = threadIdx.x;
    const int w   = tid >> 6;       // wave 0..3: owns units u in [16w, 16w+16)
    const int l   = tid & 63;
    const int q   = l >> 4;         // quad
    const int col = l & 15;
    const int b0  = blockIdx.x * MB;
    const int u   = 16 * w + col;   // this lane's unit index

    // ---- persistent B fragments: W_hh (2 K-chunks) + [W_ih | bias] per gate s ----
    // B layout: lane holds B[k = 8q+j][n = col]; n = 64*s + u -> gate-row r
    half8 bh[4][2];
    half8 bx[4];
    float bias_dummy;
    #pragma unroll
    for (int s = 0; s < 4; ++s) {
        const int r = 64 * s + u;
        #pragma unroll
        for (int c = 0; c < 2; ++c) {
            const float* p = W_hh + r * HH + 32 * c + 8 * q;
            half8 v;
            #pragma unroll
            for (int j = 0; j < 8; ++j) v[j] = (_Float16)p[j];
            bh[s][c] = v;
        }
        half8 vx = (half8)(_Float16)0.f;
        if (q == 0) {   // k<8 slots: k=0..3 -> W_ih, k=4 -> bias (A supplies 1.0)
            #pragma unroll
            for (int j = 0; j < 4; ++j) vx[j] = (_Float16)W_ih[r * 4 + j];
            vx[4] = (_Float16)(b_ih[r] + b_hh[r]);
        }
        bx[s] = vx;
    }

    // zero initial hidden state
    {
        _Float16* hz = &h_sh[0][0];
        for (int i = tid; i < 2 * MB * HSTR; i += 256) hz[i] = (_Float16)0.f;
    }

    float cst[4] = {0.f, 0.f, 0.f, 0.f};   // fp32 cell state, 4 batches per lane

    #pragma unroll 1
    for (int t = 0; t < TT; ++t) {
        if ((t & 63) == 0) {
            // refill x chunk: x[b0+m][t..t+63][0..3] -> x_sh[m][tt], f16
            __syncthreads();   // also covers initial h zeroing at t=0
            #pragma unroll
            for (int it = 0; it < 4; ++it) {
                int idx = tid + it * 256;           // 0..1023
                int m = idx >> 6, tt = idx & 63;
                float4 v = *(const float4*)(x + ((size_t)(b0 + m) * TT + t + tt) * 4);
                _Float16* d = &x_sh[m * XSTR + tt * 4];
                d[0] = (_Float16)v.x; d[1] = (_Float16)v.y;
                d[2] = (_Float16)v.z; d[3] = (_Float16)v.w;
            }
            __syncthreads();
        }

        // ---- A fragments: A[m = col][k = 8q+j] ----
        const _Float16* hb = h_sh[t & 1];
        half8 ah0 = *(const half8*)&hb[col * HSTR + 8 * q];        // k = 0..31
        half8 ah1 = *(const half8*)&hb[col * HSTR + 32 + 8 * q];   // k = 32..63
        half8 ax;
        {
            // lanes q>0 multiply against zeroed B slots -> values are don't-care
            half4 xv = *(const half4*)&x_sh[col * XSTR + (t & 63) * 4];
            ax[0] = xv[0]; ax[1] = xv[1]; ax[2] = xv[2]; ax[3] = xv[3];
            ax[4] = (_Float16)1.0f;                                 // bias multiplier
            ax[5] = (_Float16)0.f; ax[6] = (_Float16)0.f; ax[7] = (_Float16)0.f;
        }

        // ---- gates: D[m = 4q+j][n] ; tile s -> gate s of unit u ----
        f32x4 acc[4];
        #pragma unroll
        for (int s = 0; s < 4; ++s) {
            f32x4 a = {0.f, 0.f, 0.f, 0.f};
            a = __builtin_amdgcn_mfma_f32_16x16x32_f16(ax,  bx[s],    a, 0, 0, 0);
            a = __builtin_amdgcn_mfma_f32_16x16x32_f16(ah0, bh[s][0], a, 0, 0, 0);
            a = __builtin_amdgcn_mfma_f32_16x16x32_f16(ah1, bh[s][1], a, 0, 0, 0);
            acc[s] = a;
        }

        // ---- cell update: lane-local, c in fp32 registers ----
        _Float16* hw = h_sh[(t & 1) ^ 1];
        #pragma unroll
        for (int j = 0; j < 4; ++j) {
            float gi = acc[0][j], gf = acc[1][j], gg = acc[2][j], go = acc[3][j];
            cst[j] = sigm(gf) * cst[j] + sigm(gi) * tanh_f(gg);
            float hn = sigm(go) * tanh_f(cst[j]);
            hw[(4 * q + j) * HSTR + u] = (_Float16)hn;
        }
        __syncthreads();
    }

    // ---- FC epilogue: final h is in h_sh[0] ----
    if (tid < MB * 4) {
        int b = tid >> 2, o = tid & 3;
        float s = b_fc[o];
        const float* wf = W_fc + o * HH;
        #pragma unroll
        for (int k = 0; k < HH; ++k)
            s = fmaf((float)h_sh[0][b * HSTR + k], wf[k], s);
        out[(size_t)(b0 + b) * 4 + o] = s;
    }
}

extern "C" void kernel_launch(void* const* d_in, const int* in_sizes, int n_in,
                              void* d_out, int out_size, void* d_ws, size_t ws_size,
                              hipStream_t stream) {
    const float* x    = (const float*)d_in[0];
    const float* W_ih = (const float*)d_in[1];
    const float* W_hh = (const float*)d_in[2];
    const float* b_ih = (const float*)d_in[3];
    const float* b_hh = (const float*)d_in[4];
    const float* W_fc = (const float*)d_in[5];
    const float* b_fc = (const float*)d_in[6];
    float* out = (float*)d_out;
    lstm_mfma<<<2048 / MB, 256, 0, stream>>>(x, W_ih, W_hh, b_ih, b_hh, W_fc, b_fc, out);
}

// Round 3
// 310.160 us; speedup vs baseline: 2.4868x; 1.0222x over previous
//
#include <hip/hip_runtime.h>

typedef _Float16 half8 __attribute__((ext_vector_type(8)));
typedef _Float16 half4 __attribute__((ext_vector_type(4)));
typedef float f32x4 __attribute__((ext_vector_type(4)));

#define TT 512
#define HH 64
#define MB 8      // batches per block -> 256 blocks
#define S  104    // state row stride (f16): [h(64)|x(4)|1|zeros(27)|pad(8)]
                  // 208B row -> b128 B-frag reads are bank-conflict-free

__device__ __forceinline__ float sigm(float x) {
    return __builtin_amdgcn_rcpf(1.f + __builtin_amdgcn_exp2f(-1.4426950408889634f * x));
}
__device__ __forceinline__ float tanh_f(float x) {
    return 1.f - 2.f * __builtin_amdgcn_rcpf(1.f + __builtin_amdgcn_exp2f(2.8853900817779268f * x));
}

__global__ __launch_bounds__(512, 1)
void lstm_v3(const float* __restrict__ x,
             const float* __restrict__ W_ih,
             const float* __restrict__ W_hh,
             const float* __restrict__ b_ih,
             const float* __restrict__ b_hh,
             const float* __restrict__ W_fc,
             const float* __restrict__ b_fc,
             float* __restrict__ out)
{
    // double-buffered state: 16 rows (8 real batches + 8 garbage-contained)
    __shared__ __align__(16) _Float16 st[2][16 * S];

    const int tid = threadIdx.x;
    const int w   = tid >> 6;      // wave 0..7
    const int l   = tid & 63;
    const int q   = l >> 4;
    const int col = l & 15;
    const int b0  = blockIdx.x * MB;

    // ---- persistent A fragments (weights), 2 tiles per wave ----
    // tile tau = 2w+p covers gate-rows Wrow(tau,m) = 64*(m&3) + 4*tau + (m>>2)
    // A layout: lane (q,col) holds A[m=col][k=8q+j]
    half8 aw[2][3];
    #pragma unroll
    for (int p = 0; p < 2; ++p) {
        const int tau = 2 * w + p;
        const int r   = 64 * (col & 3) + 4 * tau + (col >> 2);
        #pragma unroll
        for (int c = 0; c < 2; ++c) {
            const float* src = W_hh + r * HH + 32 * c + 8 * q;
            half8 v;
            #pragma unroll
            for (int j = 0; j < 8; ++j) v[j] = (_Float16)src[j];
            aw[p][c] = v;
        }
        half8 v;
        #pragma unroll
        for (int j = 0; j < 8; ++j) v[j] = (_Float16)0.f;
        if (q == 0) {   // k = 64..67 -> W_ih, k = 68 -> bias, rest 0
            #pragma unroll
            for (int j = 0; j < 4; ++j) v[j] = (_Float16)W_ih[r * 4 + j];
            v[4] = (_Float16)(b_ih[r] + b_hh[r]);
        }
        aw[p][2] = v;
    }

    // ---- init LDS: zero everything, then ones at elem 68, x_0 at 64..67 ----
    {
        _Float16* p0 = &st[0][0];
        for (int i = tid; i < 2 * 16 * S; i += 512) p0[i] = (_Float16)0.f;
    }
    __syncthreads();
    if (tid < 32) st[tid >> 4][(tid & 15) * S + 68] = (_Float16)1.0f;

    float4 xnext;
    if (tid < MB) {
        const float4* xb = (const float4*)(x + (size_t)(b0 + tid) * TT * 4);
        float4 x0 = xb[0];
        _Float16* d = &st[0][tid * S + 64];
        d[0] = (_Float16)x0.x; d[1] = (_Float16)x0.y;
        d[2] = (_Float16)x0.z; d[3] = (_Float16)x0.w;
        xnext = xb[1];
    }
    __syncthreads();

    float cst[2] = {0.f, 0.f};

    #pragma unroll 2
    for (int t = 0; t < TT; ++t) {
        const int rb = t & 1, wb = rb ^ 1;
        const _Float16* sr = &st[rb][0];

        // B fragments (shared by both tiles): B[k=8q+j][n=col] = state[col][k]
        half8 bh0 = *(const half8*)&sr[col * S +      8 * q];   // k 0..31
        half8 bh1 = *(const half8*)&sr[col * S + 32 + 8 * q];   // k 32..63
        half8 bx  = *(const half8*)&sr[col * S + 64 + 8 * q];   // k 64..95 (x|1|0)

        // write x_{t+1} into the write buffer; prefetch x_{t+2}
        if (tid < MB) {
            _Float16* d = &st[wb][tid * S + 64];
            half4 hx;
            hx[0] = (_Float16)xnext.x; hx[1] = (_Float16)xnext.y;
            hx[2] = (_Float16)xnext.z; hx[3] = (_Float16)xnext.w;
            *(half4*)d = hx;
            const int tn = (t + 2 < TT) ? (t + 2) : (TT - 1);
            xnext = *(const float4*)(x + ((size_t)(b0 + tid) * TT + tn) * 4);
        }

        f32x4 acc0 = {0.f, 0.f, 0.f, 0.f};
        f32x4 acc1 = {0.f, 0.f, 0.f, 0.f};
        acc0 = __builtin_amdgcn_mfma_f32_16x16x32_f16(aw[0][2], bx,  acc0, 0, 0, 0);
        acc1 = __builtin_amdgcn_mfma_f32_16x16x32_f16(aw[1][2], bx,  acc1, 0, 0, 0);
        acc0 = __builtin_amdgcn_mfma_f32_16x16x32_f16(aw[0][0], bh0, acc0, 0, 0, 0);
        acc1 = __builtin_amdgcn_mfma_f32_16x16x32_f16(aw[1][0], bh0, acc1, 0, 0, 0);
        acc0 = __builtin_amdgcn_mfma_f32_16x16x32_f16(aw[0][1], bh1, acc0, 0, 0, 0);
        acc1 = __builtin_amdgcn_mfma_f32_16x16x32_f16(aw[1][1], bh1, acc1, 0, 0, 0);

        // cell update: 2 cells/lane (unit u = 8w+4p+q, batch col); regs j = i,f,g,o
        _Float16* sw = &st[wb][0];
        #pragma unroll
        for (int p = 0; p < 2; ++p) {
            const f32x4 a = p ? acc1 : acc0;
            const float gi = a[0], gf = a[1], gg = a[2], go = a[3];
            float c = sigm(gf) * cst[p] + sigm(gi) * tanh_f(gg);
            cst[p] = c;
            const float hn = sigm(go) * tanh_f(c);
            sw[col * S + (8 * w + 4 * p + q)] = (_Float16)hn;
        }
        __syncthreads();
    }

    // ---- FC epilogue: h_512 lives in st[0] rows 0..7, cols 0..63 ----
    if (tid < MB * 4) {
        const int b = tid >> 2, o = tid & 3;
        float s = b_fc[o];
        const float* wf = W_fc + o * HH;
        #pragma unroll
        for (int k = 0; k < HH; ++k)
            s = fmaf((float)st[0][b * S + k], wf[k], s);
        out[(size_t)(b0 + b) * 4 + o] = s;
    }
}

extern "C" void kernel_launch(void* const* d_in, const int* in_sizes, int n_in,
                              void* d_out, int out_size, void* d_ws, size_t ws_size,
                              hipStream_t stream) {
    const float* x    = (const float*)d_in[0];
    const float* W_ih = (const float*)d_in[1];
    const float* W_hh = (const float*)d_in[2];
    const float* b_ih = (const float*)d_in[3];
    const float* b_hh = (const float*)d_in[4];
    const float* W_fc = (const float*)d_in[5];
    const float* b_fc = (const float*)d_in[6];
    float* out = (float*)d_out;
    lstm_v3<<<2048 / MB, 512, 0, stream>>>(x, W_ih, W_hh, b_ih, b_hh, W_fc, b_fc, out);
}